// Round 1
// baseline (203.918 us; speedup 1.0000x reference)
//
#include <hip/hip_runtime.h>
#include <hip/hip_bf16.h>

#define B_ 32
#define N_ 128
#define D_ 512
#define A_ 512
#define R_ (B_*N_)     // 4096 rows
#define OC (2*A_)      // 1024 cols in fused Y

// ---------------- Kernel 1: Y = X * [W1;W2]^T + [b1;b2] ----------------
// Y[r][c]: c<512 -> x1 (W1), c>=512 -> x2 (W2). fp32 tiled GEMM.
#define BM 64
#define BN 64
#define BK 16

__global__ __launch_bounds__(256) void k1_gemm(
    const float* __restrict__ X,
    const float* __restrict__ W1, const float* __restrict__ b1,
    const float* __restrict__ W2, const float* __restrict__ b2,
    float* __restrict__ Y)
{
    __shared__ float Xs[BK][BM + 4];
    __shared__ float Ws[BK][BN + 4];
    const int t  = threadIdx.x;
    const int bm = blockIdx.x;           // 0..63
    const int bn = blockIdx.y;           // 0..15
    const float* Wb = (bn < 8) ? W1 : W2;
    const float* bb = (bn < 8) ? b1 : b2;
    const int wc0  = (bn & 7) * BN;      // col offset within the W half
    const int row0 = bm * BM;

    const int tx = t & 15;
    const int ty = t >> 4;

    const int lm = t >> 2;               // 0..63
    const int lk = (t & 3) * 4;          // 0,4,8,12

    float acc[4][4] = {};

    for (int k0 = 0; k0 < D_; k0 += BK) {
        float4 xv = *(const float4*)&X [(size_t)(row0 + lm) * D_ + k0 + lk];
        float4 wv = *(const float4*)&Wb[(size_t)(wc0  + lm) * D_ + k0 + lk];
        Xs[lk+0][lm] = xv.x; Xs[lk+1][lm] = xv.y; Xs[lk+2][lm] = xv.z; Xs[lk+3][lm] = xv.w;
        Ws[lk+0][lm] = wv.x; Ws[lk+1][lm] = wv.y; Ws[lk+2][lm] = wv.z; Ws[lk+3][lm] = wv.w;
        __syncthreads();
#pragma unroll
        for (int k = 0; k < BK; ++k) {
            float4 xa = *(const float4*)&Xs[k][ty*4];
            float4 wb = *(const float4*)&Ws[k][tx*4];
            float xr[4] = {xa.x, xa.y, xa.z, xa.w};
            float wr[4] = {wb.x, wb.y, wb.z, wb.w};
#pragma unroll
            for (int ii = 0; ii < 4; ++ii)
#pragma unroll
                for (int jj = 0; jj < 4; ++jj)
                    acc[ii][jj] = fmaf(xr[ii], wr[jj], acc[ii][jj]);
        }
        __syncthreads();
    }

#pragma unroll
    for (int ii = 0; ii < 4; ++ii) {
        int row = row0 + ty*4 + ii;
        float4 o;
        o.x = acc[ii][0] + bb[wc0 + tx*4 + 0];
        o.y = acc[ii][1] + bb[wc0 + tx*4 + 1];
        o.z = acc[ii][2] + bb[wc0 + tx*4 + 2];
        o.w = acc[ii][3] + bb[wc0 + tx*4 + 3];
        *(float4*)&Y[(size_t)row * OC + bn*BN + tx*4] = o;
    }
}

// ---------------- Kernel 2: out[b,i,j] = wsum - 2*sum_a wo[a]/(exp(2s)+1) + bout
// s = x1[b,j,a] + x2[b,i+1,a];  tanh(s) = 1 - 2/(e^{2s}+1)
__global__ __launch_bounds__(256) void k2_tanh(
    const float* __restrict__ Y,
    const float* __restrict__ Wout,
    const float* __restrict__ bout,
    float* __restrict__ out)
{
    __shared__ float x1s[16][516];
    __shared__ float x2s[16][516];
    __shared__ float wo[A_];
    __shared__ float wsum_s[4];

    const int t  = threadIdx.x;
    const int jt = blockIdx.x;    // 0..7   j-tile
    const int it = blockIdx.y;    // 0..7   i-tile
    const int b  = blockIdx.z;    // 0..31

    // load Wout to LDS + block-reduce its sum
    float ws = 0.f;
    for (int k = t; k < A_; k += 256) { float w = Wout[k]; wo[k] = w; ws += w; }
#pragma unroll
    for (int off = 32; off >= 1; off >>= 1) ws += __shfl_down(ws, off, 64);
    if ((t & 63) == 0) wsum_s[t >> 6] = ws;

    const float* yb = Y + (size_t)(b * N_) * OC;
#pragma unroll
    for (int q = 0; q < 8; ++q) {
        int f  = t + 256*q;           // 0..2047
        int r  = f >> 7;              // 0..15
        int a4 = (f & 127) << 2;      // 0..508
        float4 v1 = *(const float4*)&yb[(size_t)(jt*16 + r) * OC + a4];
        *(float4*)&x1s[r][a4] = v1;
        int i2 = it*16 + r + 1; if (i2 > 127) i2 = 127;   // clamp (guarded at store)
        float4 v2 = *(const float4*)&yb[(size_t)i2 * OC + A_ + a4];
        *(float4*)&x2s[r][a4] = v2;
    }
    __syncthreads();

    float wsum = wsum_s[0] + wsum_s[1] + wsum_s[2] + wsum_s[3];

    const int jl = t & 15;
    const int il = t >> 4;
    const float* r1 = x1s[jl];
    const float* r2 = x2s[il];

    const float C = 2.8853900817779268f;   // 2*log2(e)
    float acc = 0.f;
#pragma unroll 2
    for (int a = 0; a < A_; a += 4) {
        float4 u = *(const float4*)&r1[a];
        float4 v = *(const float4*)&r2[a];
        float4 w = *(const float4*)&wo[a];
        float e0 = __builtin_amdgcn_exp2f((u.x + v.x) * C);
        acc += w.x * __builtin_amdgcn_rcpf(e0 + 1.f);
        float e1 = __builtin_amdgcn_exp2f((u.y + v.y) * C);
        acc += w.y * __builtin_amdgcn_rcpf(e1 + 1.f);
        float e2 = __builtin_amdgcn_exp2f((u.z + v.z) * C);
        acc += w.z * __builtin_amdgcn_rcpf(e2 + 1.f);
        float e3 = __builtin_amdgcn_exp2f((u.w + v.w) * C);
        acc += w.w * __builtin_amdgcn_rcpf(e3 + 1.f);
    }

    const int i = it*16 + il;
    const int j = jt*16 + jl;
    if (i < 127)
        out[((size_t)(b*127) + i) * 128 + j] = wsum - 2.f*acc + bout[0];
}

extern "C" void kernel_launch(void* const* d_in, const int* in_sizes, int n_in,
                              void* d_out, int out_size, void* d_ws, size_t ws_size,
                              hipStream_t stream) {
    const float* x    = (const float*)d_in[0];
    const float* W1   = (const float*)d_in[1];
    const float* b1   = (const float*)d_in[2];
    const float* W2   = (const float*)d_in[3];
    const float* b2   = (const float*)d_in[4];
    const float* Wout = (const float*)d_in[5];
    const float* bout = (const float*)d_in[6];
    float* out = (float*)d_out;
    float* Y   = (float*)d_ws;   // 4096 x 1024 fp32 = 16 MB

    dim3 g1(R_/BM, OC/BN);       // (64, 16)
    k1_gemm<<<g1, 256, 0, stream>>>(x, W1, b1, W2, b2, Y);

    dim3 g2(8, 8, B_);           // j-tiles, i-tiles, batch
    k2_tanh<<<g2, 256, 0, stream>>>(Y, Wout, bout, out);
}

// Round 3
// 126.693 us; speedup vs baseline: 1.6095x; 1.6095x over previous
//
#include <hip/hip_runtime.h>
#include <hip/hip_bf16.h>

#define B_ 32
#define N_ 128
#define D_ 512
#define A_ 512
#define R_ (B_*N_)     // 4096 rows
#define OC (2*A_)      // 1024 cols in fused Y

typedef __attribute__((ext_vector_type(8))) short  frag_ab;   // 8 bf16
typedef __attribute__((ext_vector_type(4))) float  frag_cd;   // 4 f32

// pack two fp32 -> two bf16 (round-half-up) in one uint, a in low half
__device__ inline unsigned pack2bf(float a, float b) {
    unsigned ua = __builtin_bit_cast(unsigned, a) + 0x8000u;
    unsigned ub = __builtin_bit_cast(unsigned, b) + 0x8000u;
    return __builtin_amdgcn_perm(ub, ua, 0x07060302);  // bytes: [ub.3 ub.2 ua.3 ua.2]
}

// ---------------- Kernel 1: Y = X * [W1;W2]^T + [b1;b2]  (bf16 MFMA) ------
// 128x128 tile, BK=32, 4 waves (2x2), 16x16x32 bf16 MFMA, fp32 accumulate.
__global__ __launch_bounds__(256) void k1_mfma(
    const float* __restrict__ X,
    const float* __restrict__ W1, const float* __restrict__ b1,
    const float* __restrict__ W2, const float* __restrict__ b2,
    float* __restrict__ Y)
{
    __shared__ unsigned short As[128*32];
    __shared__ unsigned short Bs[128*32];

    const int t    = threadIdx.x;
    const int lane = t & 63;
    const int wid  = t >> 6;          // 0..3
    const int wr   = wid >> 1;        // wave row (0..1)
    const int wc   = wid & 1;         // wave col (0..1)
    const int row0 = blockIdx.x * 128;
    const int col0 = blockIdx.y * 128;           // in fused-OC space
    const float* Wb = (col0 < A_) ? W1 : W2;     // 128 | 512, so whole tile in one half
    const float* bb = (col0 < A_) ? b1 : b2;
    const int wrow0 = col0 & (A_-1);

    const int srow = t >> 2;          // 0..63 (staging row, q adds 64)
    const int sk8  = (t & 3) * 8;     // 0,8,16,24

    frag_cd acc[4][4];
#pragma unroll
    for (int i = 0; i < 4; ++i)
#pragma unroll
        for (int j = 0; j < 4; ++j) acc[i][j] = frag_cd{0.f,0.f,0.f,0.f};

    const int fr = lane & 15;
    const int ko = (lane >> 4) * 8;

    for (int k0 = 0; k0 < D_; k0 += 32) {
        // global -> regs (fp32)
        float4 xv[2][2], wv[2][2];
#pragma unroll
        for (int q = 0; q < 2; ++q) {
            const int row = q*64 + srow;
            const float* px = &X [(size_t)(row0  + row) * D_ + k0 + sk8];
            const float* pw = &Wb[(size_t)(wrow0 + row) * D_ + k0 + sk8];
            xv[q][0] = *(const float4*)px;  xv[q][1] = *(const float4*)(px+4);
            wv[q][0] = *(const float4*)pw;  wv[q][1] = *(const float4*)(pw+4);
        }
        __syncthreads();   // previous iteration's fragment reads complete
        // regs -> LDS (bf16)
#pragma unroll
        for (int q = 0; q < 2; ++q) {
            const int row = q*64 + srow;
            uint4 pa, pb;
            pa.x = pack2bf(xv[q][0].x, xv[q][0].y);
            pa.y = pack2bf(xv[q][0].z, xv[q][0].w);
            pa.z = pack2bf(xv[q][1].x, xv[q][1].y);
            pa.w = pack2bf(xv[q][1].z, xv[q][1].w);
            pb.x = pack2bf(wv[q][0].x, wv[q][0].y);
            pb.y = pack2bf(wv[q][0].z, wv[q][0].w);
            pb.z = pack2bf(wv[q][1].x, wv[q][1].y);
            pb.w = pack2bf(wv[q][1].z, wv[q][1].w);
            *reinterpret_cast<uint4*>(&As[row*32 + sk8]) = pa;
            *reinterpret_cast<uint4*>(&Bs[row*32 + sk8]) = pb;
        }
        __syncthreads();
        // LDS -> fragments -> MFMA
        frag_ab af[4], bfv[4];
#pragma unroll
        for (int fi = 0; fi < 4; ++fi)
            af[fi]  = *reinterpret_cast<const frag_ab*>(&As[(wr*64 + fi*16 + fr)*32 + ko]);
#pragma unroll
        for (int fj = 0; fj < 4; ++fj)
            bfv[fj] = *reinterpret_cast<const frag_ab*>(&Bs[(wc*64 + fj*16 + fr)*32 + ko]);
#pragma unroll
        for (int fi = 0; fi < 4; ++fi)
#pragma unroll
            for (int fj = 0; fj < 4; ++fj)
                acc[fi][fj] = __builtin_amdgcn_mfma_f32_16x16x32_bf16(
                    af[fi], bfv[fj], acc[fi][fj], 0, 0, 0);
    }

    // epilogue: C/D layout col=lane&15, row=(lane>>4)*4+r  (m89-verified)
#pragma unroll
    for (int fi = 0; fi < 4; ++fi) {
        const int rr = row0 + wr*64 + fi*16 + (lane >> 4)*4;
#pragma unroll
        for (int fj = 0; fj < 4; ++fj) {
            const int cc = col0 + wc*64 + fj*16 + (lane & 15);
            const float bias = bb[cc & (A_-1)];
#pragma unroll
            for (int r = 0; r < 4; ++r)
                Y[(size_t)(rr + r) * OC + cc] = acc[fi][fj][r] + bias;
        }
    }
}

// ---------------- Kernel 2 ----------------
// out[b,i,j] = wsum - 2*sum_a wo[a]/(1 + E1[j,a]*E2[i+1,a]) + bout
// E1 = exp2(C*x1), E2 = exp2(C*x2) computed during staging (exp factorization).
#define ACH 64

__global__ __launch_bounds__(256) void k2_tanh(
    const float* __restrict__ Y,
    const float* __restrict__ Wout,
    const float* __restrict__ bout,
    float* __restrict__ out)
{
    __shared__ float e1s[32][ACH + 4];
    __shared__ float e2s[32][ACH + 4];
    __shared__ float wo[A_];
    __shared__ float wsum_s[4];

    const int t  = threadIdx.x;
    const int jt = blockIdx.x;    // 0..3  (j-tile of 32)
    const int it = blockIdx.y;    // 0..3  (i-tile of 32)
    const int b  = blockIdx.z;    // 0..31

    float ws = 0.f;
    for (int k = t; k < A_; k += 256) { float w = Wout[k]; wo[k] = w; ws += w; }
#pragma unroll
    for (int off = 32; off >= 1; off >>= 1) ws += __shfl_down(ws, off, 64);
    if ((t & 63) == 0) wsum_s[t >> 6] = ws;

    const float* yb = Y + (size_t)b * N_ * OC;
    const int jl = t & 15;
    const int il = t >> 4;
    const float C = 2.8853900817779268f;   // 2*log2(e)

    float a00 = 0.f, a01 = 0.f, a10 = 0.f, a11 = 0.f;

    const int sr = t >> 4;          // staging row 0..15 (q adds 16)
    const int sc = (t & 15) * 4;    // staging col 0..60

    for (int a0 = 0; a0 < A_; a0 += ACH) {
        __syncthreads();  // previous chunk's reads complete (also fences wo/wsum_s first time)
#pragma unroll
        for (int q = 0; q < 2; ++q) {
            const int r = q*16 + sr;                   // 0..31
            float4 v1 = *(const float4*)&yb[(size_t)(jt*32 + r) * OC + a0 + sc];
            e1s[r][sc+0] = __builtin_amdgcn_exp2f(C * v1.x);
            e1s[r][sc+1] = __builtin_amdgcn_exp2f(C * v1.y);
            e1s[r][sc+2] = __builtin_amdgcn_exp2f(C * v1.z);
            e1s[r][sc+3] = __builtin_amdgcn_exp2f(C * v1.w);
            int i2 = it*32 + r + 1; if (i2 > 127) i2 = 127;
            float4 v2 = *(const float4*)&yb[(size_t)i2 * OC + A_ + a0 + sc];
            e2s[r][sc+0] = __builtin_amdgcn_exp2f(C * v2.x);
            e2s[r][sc+1] = __builtin_amdgcn_exp2f(C * v2.y);
            e2s[r][sc+2] = __builtin_amdgcn_exp2f(C * v2.z);
            e2s[r][sc+3] = __builtin_amdgcn_exp2f(C * v2.w);
        }
        __syncthreads();
#pragma unroll 2
        for (int c = 0; c < ACH; c += 4) {
            float4 u0 = *(const float4*)&e1s[jl     ][c];
            float4 u1 = *(const float4*)&e1s[jl + 16][c];
            float4 v0 = *(const float4*)&e2s[il     ][c];
            float4 v1 = *(const float4*)&e2s[il + 16][c];
            float4 w  = *(const float4*)&wo[a0 + c];
            a00 += w.x * __builtin_amdgcn_rcpf(fmaf(u0.x, v0.x, 1.f));
            a01 += w.x * __builtin_amdgcn_rcpf(fmaf(u1.x, v0.x, 1.f));
            a10 += w.x * __builtin_amdgcn_rcpf(fmaf(u0.x, v1.x, 1.f));
            a11 += w.x * __builtin_amdgcn_rcpf(fmaf(u1.x, v1.x, 1.f));
            a00 += w.y * __builtin_amdgcn_rcpf(fmaf(u0.y, v0.y, 1.f));
            a01 += w.y * __builtin_amdgcn_rcpf(fmaf(u1.y, v0.y, 1.f));
            a10 += w.y * __builtin_amdgcn_rcpf(fmaf(u0.y, v1.y, 1.f));
            a11 += w.y * __builtin_amdgcn_rcpf(fmaf(u1.y, v1.y, 1.f));
            a00 += w.z * __builtin_amdgcn_rcpf(fmaf(u0.z, v0.z, 1.f));
            a01 += w.z * __builtin_amdgcn_rcpf(fmaf(u1.z, v0.z, 1.f));
            a10 += w.z * __builtin_amdgcn_rcpf(fmaf(u0.z, v1.z, 1.f));
            a11 += w.z * __builtin_amdgcn_rcpf(fmaf(u1.z, v1.z, 1.f));
            a00 += w.w * __builtin_amdgcn_rcpf(fmaf(u0.w, v0.w, 1.f));
            a01 += w.w * __builtin_amdgcn_rcpf(fmaf(u1.w, v0.w, 1.f));
            a10 += w.w * __builtin_amdgcn_rcpf(fmaf(u0.w, v1.w, 1.f));
            a11 += w.w * __builtin_amdgcn_rcpf(fmaf(u1.w, v1.w, 1.f));
        }
    }

    const float wsum = wsum_s[0] + wsum_s[1] + wsum_s[2] + wsum_s[3];
    const float bo   = bout[0];
    const int i0 = it*32 + il;        // x2-row = i0+1
    const int j0 = jt*32 + jl;

    if (i0 < 127)      out[((size_t)(b*127) + i0     ) * 128 + j0     ] = wsum - 2.f*a00 + bo;
    if (i0 < 127)      out[((size_t)(b*127) + i0     ) * 128 + j0 + 16] = wsum - 2.f*a01 + bo;
    if (i0 + 16 < 127) out[((size_t)(b*127) + i0 + 16) * 128 + j0     ] = wsum - 2.f*a10 + bo;
    if (i0 + 16 < 127) out[((size_t)(b*127) + i0 + 16) * 128 + j0 + 16] = wsum - 2.f*a11 + bo;
}

extern "C" void kernel_launch(void* const* d_in, const int* in_sizes, int n_in,
                              void* d_out, int out_size, void* d_ws, size_t ws_size,
                              hipStream_t stream) {
    const float* x    = (const float*)d_in[0];
    const float* W1   = (const float*)d_in[1];
    const float* b1   = (const float*)d_in[2];
    const float* W2   = (const float*)d_in[3];
    const float* b2   = (const float*)d_in[4];
    const float* Wout = (const float*)d_in[5];
    const float* bout = (const float*)d_in[6];
    float* out = (float*)d_out;
    float* Y   = (float*)d_ws;   // 4096 x 1024 fp32 = 16 MB

    dim3 g1(R_/128, OC/128);     // (32, 8) = 256 blocks
    k1_mfma<<<g1, 256, 0, stream>>>(x, W1, b1, W2, b2, Y);

    dim3 g2(4, 4, B_);           // j-tiles, i-tiles, batch
    k2_tanh<<<g2, 256, 0, stream>>>(Y, Wout, bout, out);
}